// Round 2
// baseline (268.468 us; speedup 1.0000x reference)
//
#include <hip/hip_runtime.h>

// Problem constants (from reference setup_inputs) — all tensors are float32.
#define B_DIM 2
#define C_DIM 64
#define N_DIM 1024
#define E_DIM 32
#define BE_DIM (B_DIM * E_DIM)   // 64

// ---------------------------------------------------------------------------
// Kernel 1: t[b,e,n] = sum_c th12[e,c] * emb[b,c,n], for both parameter sets.
// Grid: (N/256, BE), block 256. ~17 MFLOP total — negligible.
// ---------------------------------------------------------------------------
__global__ __launch_bounds__(256) void compute_t_kernel(
    const float* __restrict__ emb,
    const float* __restrict__ th12_1,
    const float* __restrict__ th12_2,
    float* __restrict__ t1,
    float* __restrict__ t2)
{
    const int n  = blockIdx.x * 256 + threadIdx.x;
    const int be = blockIdx.y;
    const int b  = be >> 5;       // E=32
    const int e  = be & 31;

    const float* __restrict__ embp = emb + (size_t)b * C_DIM * N_DIM + n;
    const float* __restrict__ w1   = th12_1 + e * C_DIM;
    const float* __restrict__ w2   = th12_2 + e * C_DIM;

    float acc1 = 0.f, acc2 = 0.f;
#pragma unroll
    for (int c = 0; c < C_DIM; ++c) {
        const float x = embp[(size_t)c * N_DIM];
        acc1 = fmaf(w1[c], x, acc1);
        acc2 = fmaf(w2[c], x, acc2);
    }
    t1[be * N_DIM + n] = acc1;
    t2[be * N_DIM + n] = acc2;
}

// ---------------------------------------------------------------------------
// Kernel 2: out[b,e,i,j] = relu(2*max(t1i,t1j) + th5_1[e]*(i==j))
//                        * sigmoid(relu(2*max(t2i,t2j) + th5_2[e]*(i==j)))
// Grid: (N, BE), block 256. One row i per block; each lane produces 4
// consecutive j -> one float4 (16 B) coalesced store per lane.
// ---------------------------------------------------------------------------
__global__ __launch_bounds__(256) void edge_kernel(
    const float* __restrict__ t1,
    const float* __restrict__ t2,
    const float* __restrict__ th5_1,
    const float* __restrict__ th5_2,
    float* __restrict__ out)
{
    const int be = blockIdx.y;
    const int e  = be & 31;
    const int i  = blockIdx.x;
    const int jb = threadIdx.x * 4;

    const float* __restrict__ t1r = t1 + be * N_DIM;
    const float* __restrict__ t2r = t2 + be * N_DIM;

    const float t1i  = t1r[i];
    const float t2i  = t2r[i];
    const float th51 = th5_1[e];
    const float th52 = th5_2[e];

    const float4 a = *reinterpret_cast<const float4*>(t1r + jb);
    const float4 g = *reinterpret_cast<const float4*>(t2r + jb);

    const float v1[4] = {a.x, a.y, a.z, a.w};
    const float v2[4] = {g.x, g.y, g.z, g.w};

    float4 o;
    float* op = reinterpret_cast<float*>(&o);
#pragma unroll
    for (int k = 0; k < 4; ++k) {
        float d1 = 2.f * fmaxf(t1i, v1[k]);
        float d2 = 2.f * fmaxf(t2i, v2[k]);
        if (i == jb + k) { d1 += th51; d2 += th52; }   // diagonal term
        const float adj  = fmaxf(d1, 0.f);
        const float rg   = fmaxf(d2, 0.f);
        const float gate = 1.f / (1.f + __expf(-rg));
        op[k] = adj * gate;
    }

    float* dst = out + ((size_t)be * N_DIM + i) * N_DIM + jb;
    *reinterpret_cast<float4*>(dst) = o;
}

// ---------------------------------------------------------------------------
extern "C" void kernel_launch(void* const* d_in, const int* in_sizes, int n_in,
                              void* d_out, int out_size, void* d_ws, size_t ws_size,
                              hipStream_t stream) {
    const float* emb    = (const float*)d_in[0];
    const float* th12_1 = (const float*)d_in[1];
    // d_in[2] = th34_1 (unused by reference)
    const float* th5_1  = (const float*)d_in[3];
    const float* th12_2 = (const float*)d_in[4];
    // d_in[5] = th34_2 (unused by reference)
    const float* th5_2  = (const float*)d_in[6];
    float* out = (float*)d_out;

    float* t1 = (float*)d_ws;                       // BE*N floats = 256 KB
    float* t2 = t1 + (size_t)BE_DIM * N_DIM;        // another 256 KB

    dim3 g1(N_DIM / 256, BE_DIM);
    compute_t_kernel<<<g1, 256, 0, stream>>>(emb, th12_1, th12_2, t1, t2);

    dim3 g2(N_DIM, BE_DIM);
    edge_kernel<<<g2, 256, 0, stream>>>(t1, t2, th5_1, th5_2, out);
}